// Round 1
// baseline (1778.967 us; speedup 1.0000x reference)
//
#include <hip/hip_runtime.h>

#define NEG_SLOPE 0.2f
#define GAT_EPS 1e-16f

static __device__ __forceinline__ float leaky(float v) {
    return v > 0.0f ? v : NEG_SLOPE * v;
}

// ---- CSR build ------------------------------------------------------------

__global__ void count_kernel(const int* __restrict__ dst, int E,
                             int* __restrict__ counts) {
    int i = blockIdx.x * blockDim.x + threadIdx.x;
    if (i < E) atomicAdd(&counts[dst[i]], 1);
}

// Single-block scan: counts_off[i] (counts in) -> start offsets (out),
// row_ptr[0..N] exclusive prefix. 1024 threads, 8 elems/thread/iter.
__global__ __launch_bounds__(1024) void scan_kernel(int* __restrict__ counts_off,
                                                    int* __restrict__ row_ptr,
                                                    int N) {
    __shared__ int lds[1024];
    __shared__ int s_carry;
    const int tid = threadIdx.x;
    if (tid == 0) { s_carry = 0; row_ptr[0] = 0; }
    __syncthreads();
    const int CHUNK = 1024 * 8;
    for (int base = 0; base < N; base += CHUNK) {
        int v[8];
        int sum = 0;
        int idx0 = base + tid * 8;
        #pragma unroll
        for (int k = 0; k < 8; ++k) {
            int idx = idx0 + k;
            v[k] = (idx < N) ? counts_off[idx] : 0;
            sum += v[k];
        }
        lds[tid] = sum;
        __syncthreads();
        // Hillis-Steele inclusive scan over 1024 partial sums
        for (int ofs = 1; ofs < 1024; ofs <<= 1) {
            int t = (tid >= ofs) ? lds[tid - ofs] : 0;
            __syncthreads();
            lds[tid] += t;
            __syncthreads();
        }
        int p = s_carry + lds[tid] - sum;  // exclusive prefix at idx0
        #pragma unroll
        for (int k = 0; k < 8; ++k) {
            int idx = idx0 + k;
            if (idx < N) {
                counts_off[idx] = p;       // start offset for scatter
                p += v[k];
                row_ptr[idx + 1] = p;
            }
        }
        __syncthreads();
        if (tid == 0) s_carry += lds[1023];
        __syncthreads();
    }
}

__global__ void scatter_kernel(const int* __restrict__ src,
                               const int* __restrict__ dst, int E,
                               int* __restrict__ off, int* __restrict__ col) {
    int i = blockIdx.x * blockDim.x + threadIdx.x;
    if (i < E) {
        int d = dst[i];
        int pos = atomicAdd(&off[d], 1);
        col[pos] = src[i];
    }
}

// ---- Layer 1 node prep: h = x @ W1 (Fin=1), a_s/a_d logits ----------------

__global__ void prep1_kernel(const float* __restrict__ x,
                             const float* __restrict__ W1,   // [1,8]
                             const float* __restrict__ asw,  // [2,4]
                             const float* __restrict__ adw,  // [2,4]
                             int N,
                             float* __restrict__ h,          // [N,8]
                             float* __restrict__ a_s,        // [N,2]
                             float* __restrict__ a_d) {      // [N,2]
    int n = blockIdx.x * blockDim.x + threadIdx.x;
    if (n >= N) return;
    float xv = x[n];
    float hv[8];
    #pragma unroll
    for (int j = 0; j < 8; ++j) hv[j] = xv * W1[j];
    float4* hp = (float4*)(h + (size_t)n * 8);
    hp[0] = make_float4(hv[0], hv[1], hv[2], hv[3]);
    hp[1] = make_float4(hv[4], hv[5], hv[6], hv[7]);
    #pragma unroll
    for (int hd = 0; hd < 2; ++hd) {
        float s = 0.f, d = 0.f;
        #pragma unroll
        for (int f = 0; f < 4; ++f) {
            s += hv[hd * 4 + f] * asw[hd * 4 + f];
            d += hv[hd * 4 + f] * adw[hd * 4 + f];
        }
        a_s[n * 2 + hd] = s;
        a_d[n * 2 + hd] = d;
    }
}

// ---- Layer 2 node prep: h = in @ W2 (8x8), logits --------------------------

__global__ void prep2_kernel(const float* __restrict__ in,   // [N,8]
                             const float* __restrict__ W2,   // [8,8]
                             const float* __restrict__ asw,
                             const float* __restrict__ adw,
                             int N,
                             float* __restrict__ h,
                             float* __restrict__ a_s,
                             float* __restrict__ a_d) {
    int n = blockIdx.x * blockDim.x + threadIdx.x;
    if (n >= N) return;
    const float4* ip = (const float4*)(in + (size_t)n * 8);
    float4 i0 = ip[0], i1 = ip[1];
    float iv[8] = {i0.x, i0.y, i0.z, i0.w, i1.x, i1.y, i1.z, i1.w};
    float hv[8];
    #pragma unroll
    for (int j = 0; j < 8; ++j) {
        float acc = 0.f;
        #pragma unroll
        for (int k = 0; k < 8; ++k) acc += iv[k] * W2[k * 8 + j];
        hv[j] = acc;
    }
    float4* hp = (float4*)(h + (size_t)n * 8);
    hp[0] = make_float4(hv[0], hv[1], hv[2], hv[3]);
    hp[1] = make_float4(hv[4], hv[5], hv[6], hv[7]);
    #pragma unroll
    for (int hd = 0; hd < 2; ++hd) {
        float s = 0.f, d = 0.f;
        #pragma unroll
        for (int f = 0; f < 4; ++f) {
            s += hv[hd * 4 + f] * asw[hd * 4 + f];
            d += hv[hd * 4 + f] * adw[hd * 4 + f];
        }
        a_s[n * 2 + hd] = s;
        a_d[n * 2 + hd] = d;
    }
}

// ---- GAT aggregation: per-dst segment softmax + weighted sum ---------------

__global__ void gat_pass_kernel(const float* __restrict__ h,     // [N,8]
                                const float* __restrict__ a_s,   // [N,2]
                                const float* __restrict__ a_d,   // [N,2]
                                const int* __restrict__ row_ptr,
                                const int* __restrict__ col,
                                const float* __restrict__ bias,  // [8]
                                int N,
                                float* __restrict__ out) {       // [N,8]
    int n = blockIdx.x * blockDim.x + threadIdx.x;
    if (n >= N) return;
    int beg = row_ptr[n], end = row_ptr[n + 1];
    float2 ad = *(const float2*)(a_d + (size_t)n * 2);
    float2 as_self = *(const float2*)(a_s + (size_t)n * 2);
    float e0 = leaky(as_self.x + ad.x);
    float e1 = leaky(as_self.y + ad.y);
    float m0 = e0, m1 = e1;
    // pass 1: max
    for (int i = beg; i < end; ++i) {
        int s = col[i];
        float2 as = *(const float2*)(a_s + (size_t)s * 2);
        float t0 = leaky(as.x + ad.x);
        float t1 = leaky(as.y + ad.y);
        m0 = fmaxf(m0, t0);
        m1 = fmaxf(m1, t1);
    }
    // pass 2: exp-sum + weighted feature accumulation
    float ex0 = expf(e0 - m0);
    float ex1 = expf(e1 - m1);
    float sum0 = ex0, sum1 = ex1;
    const float4* hp = (const float4*)(h + (size_t)n * 8);
    float4 h0 = hp[0], h1 = hp[1];
    float acc[8];
    acc[0] = h0.x * ex0; acc[1] = h0.y * ex0; acc[2] = h0.z * ex0; acc[3] = h0.w * ex0;
    acc[4] = h1.x * ex1; acc[5] = h1.y * ex1; acc[6] = h1.z * ex1; acc[7] = h1.w * ex1;
    for (int i = beg; i < end; ++i) {
        int s = col[i];
        float2 as = *(const float2*)(a_s + (size_t)s * 2);
        float t0 = leaky(as.x + ad.x);
        float t1 = leaky(as.y + ad.y);
        float p0 = expf(t0 - m0);
        float p1 = expf(t1 - m1);
        sum0 += p0;
        sum1 += p1;
        const float4* sp = (const float4*)(h + (size_t)s * 8);
        float4 s0 = sp[0], s1 = sp[1];
        acc[0] += s0.x * p0; acc[1] += s0.y * p0; acc[2] += s0.z * p0; acc[3] += s0.w * p0;
        acc[4] += s1.x * p1; acc[5] += s1.y * p1; acc[6] += s1.z * p1; acc[7] += s1.w * p1;
    }
    float inv0 = 1.0f / (sum0 + GAT_EPS);
    float inv1 = 1.0f / (sum1 + GAT_EPS);
    float4* op = (float4*)(out + (size_t)n * 8);
    op[0] = make_float4(acc[0] * inv0 + bias[0], acc[1] * inv0 + bias[1],
                        acc[2] * inv0 + bias[2], acc[3] * inv0 + bias[3]);
    op[1] = make_float4(acc[4] * inv1 + bias[4], acc[5] * inv1 + bias[5],
                        acc[6] * inv1 + bias[6], acc[7] * inv1 + bias[7]);
}

// ---- Readout: y = [h2[src], h2[dst]] @ Wl + bl ------------------------------

__global__ void final_kernel(const float* __restrict__ h2,   // [N,8]
                             const int* __restrict__ srcq,
                             const int* __restrict__ dstq,
                             const float* __restrict__ Wl,    // [16,2]
                             const float* __restrict__ bl,    // [2]
                             int Q,
                             float* __restrict__ y) {         // [Q,2]
    int q = blockIdx.x * blockDim.x + threadIdx.x;
    if (q >= Q) return;
    int s = srcq[q];
    int d = dstq[q];
    const float4* sp = (const float4*)(h2 + (size_t)s * 8);
    const float4* dp = (const float4*)(h2 + (size_t)d * 8);
    float4 s0 = sp[0], s1 = sp[1];
    float4 d0 = dp[0], d1 = dp[1];
    float hs[8] = {s0.x, s0.y, s0.z, s0.w, s1.x, s1.y, s1.z, s1.w};
    float hd[8] = {d0.x, d0.y, d0.z, d0.w, d1.x, d1.y, d1.z, d1.w};
    float y0 = bl[0], y1 = bl[1];
    #pragma unroll
    for (int k = 0; k < 8; ++k) {
        y0 += hs[k] * Wl[k * 2 + 0];
        y1 += hs[k] * Wl[k * 2 + 1];
    }
    #pragma unroll
    for (int k = 0; k < 8; ++k) {
        y0 += hd[k] * Wl[(8 + k) * 2 + 0];
        y1 += hd[k] * Wl[(8 + k) * 2 + 1];
    }
    *(float2*)(y + (size_t)q * 2) = make_float2(y0, y1);
}

// ---- launch -----------------------------------------------------------------

static inline size_t align_up(size_t v, size_t a) { return (v + a - 1) & ~(a - 1); }

extern "C" void kernel_launch(void* const* d_in, const int* in_sizes, int n_in,
                              void* d_out, int out_size, void* d_ws, size_t ws_size,
                              hipStream_t stream) {
    const float* x    = (const float*)d_in[0];
    const int*   ei   = (const int*)d_in[1];
    const int*   srcq = (const int*)d_in[2];
    const int*   dstq = (const int*)d_in[3];
    const float* W1   = (const float*)d_in[4];
    const float* as1  = (const float*)d_in[5];
    const float* ad1  = (const float*)d_in[6];
    const float* b1   = (const float*)d_in[7];
    const float* W2   = (const float*)d_in[8];
    const float* as2  = (const float*)d_in[9];
    const float* ad2  = (const float*)d_in[10];
    const float* b2   = (const float*)d_in[11];
    const float* Wl   = (const float*)d_in[12];
    const float* bl   = (const float*)d_in[13];

    const int N = in_sizes[0];         // x is [N,1]
    const int E = in_sizes[1] / 2;     // edge_index [2,E]
    const int Q = in_sizes[2];

    const int* esrc = ei;
    const int* edst = ei + E;

    // workspace carve
    char* w = (char*)d_ws;
    int* row_ptr = (int*)w;  w += align_up((size_t)(N + 1) * 4, 256);
    int* off     = (int*)w;  w += align_up((size_t)N * 4, 256);
    int* col     = (int*)w;  w += align_up((size_t)E * 4, 256);
    float* h     = (float*)w; w += align_up((size_t)N * 8 * 4, 256);
    float* a_s   = (float*)w; w += align_up((size_t)N * 2 * 4, 256);
    float* a_d   = (float*)w; w += align_up((size_t)N * 2 * 4, 256);
    float* out1  = (float*)w; w += align_up((size_t)N * 8 * 4, 256);
    float* out2  = (float*)w; w += align_up((size_t)N * 8 * 4, 256);

    const int BT = 256;
    int nodeBlocks = (N + BT - 1) / BT;
    int edgeBlocks = (E + BT - 1) / BT;
    int qBlocks    = (Q + BT - 1) / BT;

    // CSR build
    hipMemsetAsync(off, 0, (size_t)N * 4, stream);
    count_kernel<<<edgeBlocks, BT, 0, stream>>>(edst, E, off);
    scan_kernel<<<1, 1024, 0, stream>>>(off, row_ptr, N);
    scatter_kernel<<<edgeBlocks, BT, 0, stream>>>(esrc, edst, E, off, col);

    // layer 1
    prep1_kernel<<<nodeBlocks, BT, 0, stream>>>(x, W1, as1, ad1, N, h, a_s, a_d);
    gat_pass_kernel<<<nodeBlocks, BT, 0, stream>>>(h, a_s, a_d, row_ptr, col, b1, N, out1);

    // layer 2
    prep2_kernel<<<nodeBlocks, BT, 0, stream>>>(out1, W2, as2, ad2, N, h, a_s, a_d);
    gat_pass_kernel<<<nodeBlocks, BT, 0, stream>>>(h, a_s, a_d, row_ptr, col, b2, N, out2);

    // readout
    final_kernel<<<qBlocks, BT, 0, stream>>>(out2, srcq, dstq, Wl, bl, Q, (float*)d_out);
}

// Round 2
// 671.413 us; speedup vs baseline: 2.6496x; 2.6496x over previous
//
#include <hip/hip_runtime.h>

#define NEG_SLOPE 0.2f
#define GAT_EPS 1e-16f

#define BSHIFT 9
#define BSIZE 512            // nodes per bucket
#define NBPAD 512            // max buckets supported (N <= 262144)

#define K3_T 512
#define K3_VPT 8
#define K3_TILE (K3_T * K3_VPT)

static __device__ __forceinline__ float leaky(float v) {
    return v > 0.0f ? v : NEG_SLOPE * v;
}

// ---- K1: per-bucket edge histogram (LDS-aggregated) ------------------------

__global__ void bucket_count_kernel(const int* __restrict__ dst, int E, int NB,
                                    int* __restrict__ bcnt) {
    __shared__ int cnt[NBPAD];
    for (int i = threadIdx.x; i < NBPAD; i += blockDim.x) cnt[i] = 0;
    __syncthreads();
    int stride = gridDim.x * blockDim.x;
    for (int i = blockIdx.x * blockDim.x + threadIdx.x; i < E; i += stride)
        atomicAdd(&cnt[dst[i] >> BSHIFT], 1);
    __syncthreads();
    for (int i = threadIdx.x; i < NB; i += blockDim.x)
        if (cnt[i]) atomicAdd(&bcnt[i], cnt[i]);
}

// ---- K2: scan of bucket counts (single block) ------------------------------

__global__ __launch_bounds__(NBPAD) void bucket_scan_kernel(
        const int* __restrict__ bcnt, int NB,
        int* __restrict__ bbase, int* __restrict__ bcursor) {
    __shared__ int lds[NBPAD];
    int tid = threadIdx.x;
    int v = (tid < NB) ? bcnt[tid] : 0;
    lds[tid] = v;
    __syncthreads();
    for (int ofs = 1; ofs < NBPAD; ofs <<= 1) {
        int t = (tid >= ofs) ? lds[tid - ofs] : 0;
        __syncthreads();
        lds[tid] += t;
        __syncthreads();
    }
    int incl = lds[tid];
    int excl = incl - v;
    if (tid < NB) { bbase[tid] = excl; bcursor[tid] = excl; }
    if (tid == NB - 1) bbase[NB] = incl;   // == E
}

// ---- K3: bucketed scatter with LDS tile reorder ----------------------------
// packed value: (src << 9) | (dst & 511); requires N <= 2^18.

__global__ __launch_bounds__(K3_T) void bin_scatter_kernel(
        const int* __restrict__ src, const int* __restrict__ dst, int E, int NB,
        int* __restrict__ bcursor, unsigned int* __restrict__ binned) {
    __shared__ int cnt[NBPAD];
    __shared__ int lstart[NBPAD];
    __shared__ int gbase[NBPAD];
    __shared__ unsigned int buf[K3_TILE];
    __shared__ unsigned short tgtb[K3_TILE];
    const int tid = threadIdx.x;
    const int t0 = blockIdx.x * K3_TILE;

    cnt[tid] = 0;
    __syncthreads();

    int b[K3_VPT];
    unsigned int v[K3_VPT];
    #pragma unroll
    for (int k = 0; k < K3_VPT; ++k) {
        int i = t0 + k * K3_T + tid;   // coalesced
        b[k] = -1;
        if (i < E) {
            int d = dst[i];
            int s = src[i];
            b[k] = d >> BSHIFT;
            v[k] = ((unsigned int)s << BSHIFT) | (unsigned int)(d & (BSIZE - 1));
            atomicAdd(&cnt[b[k]], 1);
        }
    }
    __syncthreads();

    int c = cnt[tid];
    lstart[tid] = c;
    __syncthreads();
    for (int ofs = 1; ofs < NBPAD; ofs <<= 1) {
        int t = (tid >= ofs) ? lstart[tid - ofs] : 0;
        __syncthreads();
        lstart[tid] += t;
        __syncthreads();
    }
    int excl = lstart[tid] - c;
    // reserve global space for this tile's bucket segments
    if (tid < NB) gbase[tid] = c ? atomicAdd(&bcursor[tid], c) : 0;
    __syncthreads();
    lstart[tid] = excl;
    cnt[tid] = 0;
    __syncthreads();

    // rank + reorder into LDS (bucket-sorted)
    #pragma unroll
    for (int k = 0; k < K3_VPT; ++k) {
        if (b[k] >= 0) {
            int r = atomicAdd(&cnt[b[k]], 1);
            int slot = lstart[b[k]] + r;
            buf[slot] = v[k];
            tgtb[slot] = (unsigned short)b[k];
        }
    }
    __syncthreads();

    // write out: consecutive slots of the same bucket -> consecutive addresses
    int nvalid = min(K3_TILE, E - t0);
    for (int j = tid; j < nvalid; j += K3_T) {
        int bb = tgtb[j];
        binned[gbase[bb] + (j - lstart[bb])] = buf[j];
    }
}

// ---- K4: per-bucket local scatter -> col + row_ptr -------------------------

__global__ __launch_bounds__(BSIZE) void bucket_build_kernel(
        const unsigned int* __restrict__ binned, const int* __restrict__ bbase,
        int N, int E, int* __restrict__ row_ptr, int* __restrict__ col) {
    __shared__ int cnt[BSIZE];
    __shared__ int lstart[BSIZE];
    const int b = blockIdx.x;
    const int tid = threadIdx.x;
    const int e0 = bbase[b], e1 = bbase[b + 1];
    const int n0 = b << BSHIFT;

    cnt[tid] = 0;
    __syncthreads();
    for (int i = e0 + tid; i < e1; i += BSIZE)
        atomicAdd(&cnt[binned[i] & (BSIZE - 1)], 1);
    __syncthreads();

    int c = cnt[tid];
    lstart[tid] = c;
    __syncthreads();
    for (int ofs = 1; ofs < BSIZE; ofs <<= 1) {
        int t = (tid >= ofs) ? lstart[tid - ofs] : 0;
        __syncthreads();
        lstart[tid] += t;
        __syncthreads();
    }
    int excl = lstart[tid] - c;
    __syncthreads();
    lstart[tid] = excl;
    cnt[tid] = 0;
    __syncthreads();

    int n = n0 + tid;
    if (n < N) row_ptr[n] = e0 + excl;
    if (b == 0 && tid == 0) row_ptr[N] = E;

    for (int i = e0 + tid; i < e1; i += BSIZE) {
        unsigned int v = binned[i];          // L2-warm re-read
        int dl = v & (BSIZE - 1);
        int r = atomicAdd(&cnt[dl], 1);
        col[e0 + lstart[dl] + r] = (int)(v >> BSHIFT);
    }
}

// ---- Layer 1 node prep: h = x @ W1 (Fin=1), a_s/a_d logits -----------------

__global__ void prep1_kernel(const float* __restrict__ x,
                             const float* __restrict__ W1,   // [1,8]
                             const float* __restrict__ asw,  // [2,4]
                             const float* __restrict__ adw,  // [2,4]
                             int N,
                             float* __restrict__ h,          // [N,8]
                             float* __restrict__ a_s,        // [N,2]
                             float* __restrict__ a_d) {      // [N,2]
    int n = blockIdx.x * blockDim.x + threadIdx.x;
    if (n >= N) return;
    float xv = x[n];
    float hv[8];
    #pragma unroll
    for (int j = 0; j < 8; ++j) hv[j] = xv * W1[j];
    float4* hp = (float4*)(h + (size_t)n * 8);
    hp[0] = make_float4(hv[0], hv[1], hv[2], hv[3]);
    hp[1] = make_float4(hv[4], hv[5], hv[6], hv[7]);
    #pragma unroll
    for (int hd = 0; hd < 2; ++hd) {
        float s = 0.f, d = 0.f;
        #pragma unroll
        for (int f = 0; f < 4; ++f) {
            s += hv[hd * 4 + f] * asw[hd * 4 + f];
            d += hv[hd * 4 + f] * adw[hd * 4 + f];
        }
        a_s[n * 2 + hd] = s;
        a_d[n * 2 + hd] = d;
    }
}

// ---- Layer 2 node prep: h = in @ W2 (8x8), logits --------------------------

__global__ void prep2_kernel(const float* __restrict__ in,   // [N,8]
                             const float* __restrict__ W2,   // [8,8]
                             const float* __restrict__ asw,
                             const float* __restrict__ adw,
                             int N,
                             float* __restrict__ h,
                             float* __restrict__ a_s,
                             float* __restrict__ a_d) {
    int n = blockIdx.x * blockDim.x + threadIdx.x;
    if (n >= N) return;
    const float4* ip = (const float4*)(in + (size_t)n * 8);
    float4 i0 = ip[0], i1 = ip[1];
    float iv[8] = {i0.x, i0.y, i0.z, i0.w, i1.x, i1.y, i1.z, i1.w};
    float hv[8];
    #pragma unroll
    for (int j = 0; j < 8; ++j) {
        float acc = 0.f;
        #pragma unroll
        for (int k = 0; k < 8; ++k) acc += iv[k] * W2[k * 8 + j];
        hv[j] = acc;
    }
    float4* hp = (float4*)(h + (size_t)n * 8);
    hp[0] = make_float4(hv[0], hv[1], hv[2], hv[3]);
    hp[1] = make_float4(hv[4], hv[5], hv[6], hv[7]);
    #pragma unroll
    for (int hd = 0; hd < 2; ++hd) {
        float s = 0.f, d = 0.f;
        #pragma unroll
        for (int f = 0; f < 4; ++f) {
            s += hv[hd * 4 + f] * asw[hd * 4 + f];
            d += hv[hd * 4 + f] * adw[hd * 4 + f];
        }
        a_s[n * 2 + hd] = s;
        a_d[n * 2 + hd] = d;
    }
}

// ---- GAT aggregation: single-pass segment softmax (no max; logits bounded) -

__global__ void gat_pass_kernel(const float* __restrict__ h,     // [N,8]
                                const float* __restrict__ a_s,   // [N,2]
                                const float* __restrict__ a_d,   // [N,2]
                                const int* __restrict__ row_ptr,
                                const int* __restrict__ col,
                                const float* __restrict__ bias,  // [8]
                                int N,
                                float* __restrict__ out) {       // [N,8]
    int n = blockIdx.x * blockDim.x + threadIdx.x;
    if (n >= N) return;
    int beg = row_ptr[n], end = row_ptr[n + 1];
    float2 ad = *(const float2*)(a_d + (size_t)n * 2);
    float2 as0 = *(const float2*)(a_s + (size_t)n * 2);
    // self-loop term
    float p0 = expf(leaky(as0.x + ad.x));
    float p1 = expf(leaky(as0.y + ad.y));
    float sum0 = p0, sum1 = p1;
    const float4* hp = (const float4*)(h + (size_t)n * 8);
    float4 h0 = hp[0], h1 = hp[1];
    float acc[8];
    acc[0] = h0.x * p0; acc[1] = h0.y * p0; acc[2] = h0.z * p0; acc[3] = h0.w * p0;
    acc[4] = h1.x * p1; acc[5] = h1.y * p1; acc[6] = h1.z * p1; acc[7] = h1.w * p1;
    for (int i = beg; i < end; ++i) {
        int s = col[i];
        float2 a = *(const float2*)(a_s + (size_t)s * 2);
        float q0 = expf(leaky(a.x + ad.x));
        float q1 = expf(leaky(a.y + ad.y));
        sum0 += q0;
        sum1 += q1;
        const float4* sp = (const float4*)(h + (size_t)s * 8);
        float4 s0 = sp[0], s1 = sp[1];
        acc[0] += s0.x * q0; acc[1] += s0.y * q0; acc[2] += s0.z * q0; acc[3] += s0.w * q0;
        acc[4] += s1.x * q1; acc[5] += s1.y * q1; acc[6] += s1.z * q1; acc[7] += s1.w * q1;
    }
    float inv0 = 1.0f / (sum0 + GAT_EPS);
    float inv1 = 1.0f / (sum1 + GAT_EPS);
    float4* op = (float4*)(out + (size_t)n * 8);
    op[0] = make_float4(acc[0] * inv0 + bias[0], acc[1] * inv0 + bias[1],
                        acc[2] * inv0 + bias[2], acc[3] * inv0 + bias[3]);
    op[1] = make_float4(acc[4] * inv1 + bias[4], acc[5] * inv1 + bias[5],
                        acc[6] * inv1 + bias[6], acc[7] * inv1 + bias[7]);
}

// ---- Readout: y = [h2[src], h2[dst]] @ Wl + bl -----------------------------

__global__ void final_kernel(const float* __restrict__ h2,   // [N,8]
                             const int* __restrict__ srcq,
                             const int* __restrict__ dstq,
                             const float* __restrict__ Wl,    // [16,2]
                             const float* __restrict__ bl,    // [2]
                             int Q,
                             float* __restrict__ y) {         // [Q,2]
    int q = blockIdx.x * blockDim.x + threadIdx.x;
    if (q >= Q) return;
    int s = srcq[q];
    int d = dstq[q];
    const float4* sp = (const float4*)(h2 + (size_t)s * 8);
    const float4* dp = (const float4*)(h2 + (size_t)d * 8);
    float4 s0 = sp[0], s1 = sp[1];
    float4 d0 = dp[0], d1 = dp[1];
    float hs[8] = {s0.x, s0.y, s0.z, s0.w, s1.x, s1.y, s1.z, s1.w};
    float hd[8] = {d0.x, d0.y, d0.z, d0.w, d1.x, d1.y, d1.z, d1.w};
    float y0 = bl[0], y1 = bl[1];
    #pragma unroll
    for (int k = 0; k < 8; ++k) {
        y0 += hs[k] * Wl[k * 2 + 0];
        y1 += hs[k] * Wl[k * 2 + 1];
    }
    #pragma unroll
    for (int k = 0; k < 8; ++k) {
        y0 += hd[k] * Wl[(8 + k) * 2 + 0];
        y1 += hd[k] * Wl[(8 + k) * 2 + 1];
    }
    *(float2*)(y + (size_t)q * 2) = make_float2(y0, y1);
}

// ---- launch ----------------------------------------------------------------

static inline size_t align_up(size_t v, size_t a) { return (v + a - 1) & ~(a - 1); }

extern "C" void kernel_launch(void* const* d_in, const int* in_sizes, int n_in,
                              void* d_out, int out_size, void* d_ws, size_t ws_size,
                              hipStream_t stream) {
    const float* x    = (const float*)d_in[0];
    const int*   ei   = (const int*)d_in[1];
    const int*   srcq = (const int*)d_in[2];
    const int*   dstq = (const int*)d_in[3];
    const float* W1   = (const float*)d_in[4];
    const float* as1  = (const float*)d_in[5];
    const float* ad1  = (const float*)d_in[6];
    const float* b1   = (const float*)d_in[7];
    const float* W2   = (const float*)d_in[8];
    const float* as2  = (const float*)d_in[9];
    const float* ad2  = (const float*)d_in[10];
    const float* b2   = (const float*)d_in[11];
    const float* Wl   = (const float*)d_in[12];
    const float* bl   = (const float*)d_in[13];

    const int N = in_sizes[0];         // x is [N,1]
    const int E = in_sizes[1] / 2;     // edge_index [2,E]
    const int Q = in_sizes[2];
    const int NB = (N + BSIZE - 1) >> BSHIFT;   // <= 512 for N <= 262144

    const int* esrc = ei;
    const int* edst = ei + E;

    // ---- workspace carve (with aliasing: binned region reused for node arrays)
    char* w = (char*)d_ws;
    int* col     = (int*)w;  w += align_up((size_t)E * 4, 256);
    int* row_ptr = (int*)w;  w += align_up((size_t)(N + 1) * 4, 256);
    int* bcnt    = (int*)w;  w += align_up((size_t)NBPAD * 4, 256);
    int* bbase   = (int*)w;  w += align_up((size_t)(NBPAD + 1) * 4, 256);
    int* bcursor = (int*)w;  w += align_up((size_t)NBPAD * 4, 256);
    // region X: binned (E uints) during CSR build; node arrays afterwards
    char* rx = w;
    unsigned int* binned = (unsigned int*)rx;
    float* h    = (float*)rx;                 rx += align_up((size_t)N * 8 * 4, 256);
    float* a_s  = (float*)rx;                 rx += align_up((size_t)N * 2 * 4, 256);
    float* a_d  = (float*)rx;                 rx += align_up((size_t)N * 2 * 4, 256);
    float* out1 = (float*)rx;                 rx += align_up((size_t)N * 8 * 4, 256);
    float* out2 = (float*)rx;                 // fits: 22.4MB node arrays <= 25.6MB binned

    const int BT = 256;
    int nodeBlocks = (N + BT - 1) / BT;
    int qBlocks    = (Q + BT - 1) / BT;
    int k3Blocks   = (E + K3_TILE - 1) / K3_TILE;

    // ---- CSR build (bucketed, write-coalesced)
    hipMemsetAsync(bcnt, 0, (size_t)NBPAD * 4, stream);
    bucket_count_kernel<<<1024, BT, 0, stream>>>(edst, E, NB, bcnt);
    bucket_scan_kernel<<<1, NBPAD, 0, stream>>>(bcnt, NB, bbase, bcursor);
    bin_scatter_kernel<<<k3Blocks, K3_T, 0, stream>>>(esrc, edst, E, NB, bcursor, binned);
    bucket_build_kernel<<<NB, BSIZE, 0, stream>>>(binned, bbase, N, E, row_ptr, col);

    // ---- layer 1 (node arrays overwrite dead binned region)
    prep1_kernel<<<nodeBlocks, BT, 0, stream>>>(x, W1, as1, ad1, N, h, a_s, a_d);
    gat_pass_kernel<<<nodeBlocks, BT, 0, stream>>>(h, a_s, a_d, row_ptr, col, b1, N, out1);

    // ---- layer 2
    prep2_kernel<<<nodeBlocks, BT, 0, stream>>>(out1, W2, as2, ad2, N, h, a_s, a_d);
    gat_pass_kernel<<<nodeBlocks, BT, 0, stream>>>(h, a_s, a_d, row_ptr, col, b2, N, out2);

    // ---- readout
    final_kernel<<<qBlocks, BT, 0, stream>>>(out2, srcq, dstq, Wl, bl, Q, (float*)d_out);
}

// Round 3
// 406.185 us; speedup vs baseline: 4.3797x; 1.6530x over previous
//
#include <hip/hip_runtime.h>

#define NEG_SLOPE 0.2f
#define GAT_EPS 1e-16f

#define BSHIFT 9
#define BSIZE 512            // nodes per bucket
#define NBPAD 512            // max buckets supported (N <= 262144)

#define K3_T 512
#define K3_VPT 8
#define K3_TILE (K3_T * K3_VPT)

static __device__ __forceinline__ float leaky(float v) {
    return v > 0.0f ? v : NEG_SLOPE * v;
}

// ---- K1: per-bucket edge histogram (LDS-aggregated) ------------------------

__global__ void bucket_count_kernel(const int* __restrict__ dst, int E, int NB,
                                    int* __restrict__ bcnt) {
    __shared__ int cnt[NBPAD];
    for (int i = threadIdx.x; i < NBPAD; i += blockDim.x) cnt[i] = 0;
    __syncthreads();
    int stride = gridDim.x * blockDim.x;
    for (int i = blockIdx.x * blockDim.x + threadIdx.x; i < E; i += stride)
        atomicAdd(&cnt[dst[i] >> BSHIFT], 1);
    __syncthreads();
    for (int i = threadIdx.x; i < NB; i += blockDim.x)
        if (cnt[i]) atomicAdd(&bcnt[i], cnt[i]);
}

// ---- K2: scan of bucket counts (single block) ------------------------------

__global__ __launch_bounds__(NBPAD) void bucket_scan_kernel(
        const int* __restrict__ bcnt, int NB,
        int* __restrict__ bbase, int* __restrict__ bcursor) {
    __shared__ int lds[NBPAD];
    int tid = threadIdx.x;
    int v = (tid < NB) ? bcnt[tid] : 0;
    lds[tid] = v;
    __syncthreads();
    for (int ofs = 1; ofs < NBPAD; ofs <<= 1) {
        int t = (tid >= ofs) ? lds[tid - ofs] : 0;
        __syncthreads();
        lds[tid] += t;
        __syncthreads();
    }
    int incl = lds[tid];
    int excl = incl - v;
    if (tid < NB) { bbase[tid] = excl; bcursor[tid] = excl; }
    if (tid == NB - 1) bbase[NB] = incl;   // == E
}

// ---- K3: bucketed scatter with LDS tile reorder ----------------------------
// packed value: (src << 9) | (dst & 511); requires N <= 2^18.

__global__ __launch_bounds__(K3_T) void bin_scatter_kernel(
        const int* __restrict__ src, const int* __restrict__ dst, int E, int NB,
        int* __restrict__ bcursor, unsigned int* __restrict__ binned) {
    __shared__ int cnt[NBPAD];
    __shared__ int lstart[NBPAD];
    __shared__ int gbase[NBPAD];
    __shared__ unsigned int buf[K3_TILE];
    __shared__ unsigned short tgtb[K3_TILE];
    const int tid = threadIdx.x;
    const int t0 = blockIdx.x * K3_TILE;

    cnt[tid] = 0;
    __syncthreads();

    int b[K3_VPT];
    unsigned int v[K3_VPT];
    #pragma unroll
    for (int k = 0; k < K3_VPT; ++k) {
        int i = t0 + k * K3_T + tid;   // coalesced
        b[k] = -1;
        if (i < E) {
            int d = dst[i];
            int s = src[i];
            b[k] = d >> BSHIFT;
            v[k] = ((unsigned int)s << BSHIFT) | (unsigned int)(d & (BSIZE - 1));
            atomicAdd(&cnt[b[k]], 1);
        }
    }
    __syncthreads();

    int c = cnt[tid];
    lstart[tid] = c;
    __syncthreads();
    for (int ofs = 1; ofs < NBPAD; ofs <<= 1) {
        int t = (tid >= ofs) ? lstart[tid - ofs] : 0;
        __syncthreads();
        lstart[tid] += t;
        __syncthreads();
    }
    int excl = lstart[tid] - c;
    // reserve global space for this tile's bucket segments
    if (tid < NB) gbase[tid] = c ? atomicAdd(&bcursor[tid], c) : 0;
    __syncthreads();
    lstart[tid] = excl;
    cnt[tid] = 0;
    __syncthreads();

    // rank + reorder into LDS (bucket-sorted)
    #pragma unroll
    for (int k = 0; k < K3_VPT; ++k) {
        if (b[k] >= 0) {
            int r = atomicAdd(&cnt[b[k]], 1);
            int slot = lstart[b[k]] + r;
            buf[slot] = v[k];
            tgtb[slot] = (unsigned short)b[k];
        }
    }
    __syncthreads();

    // write out: consecutive slots of the same bucket -> consecutive addresses
    int nvalid = min(K3_TILE, E - t0);
    for (int j = tid; j < nvalid; j += K3_T) {
        int bb = tgtb[j];
        binned[gbase[bb] + (j - lstart[bb])] = buf[j];
    }
}

// ---- K4: per-bucket local scatter -> col + row_ptr -------------------------

__global__ __launch_bounds__(BSIZE) void bucket_build_kernel(
        const unsigned int* __restrict__ binned, const int* __restrict__ bbase,
        int N, int E, int* __restrict__ row_ptr, int* __restrict__ col) {
    __shared__ int cnt[BSIZE];
    __shared__ int lstart[BSIZE];
    const int b = blockIdx.x;
    const int tid = threadIdx.x;
    const int e0 = bbase[b], e1 = bbase[b + 1];
    const int n0 = b << BSHIFT;

    cnt[tid] = 0;
    __syncthreads();
    for (int i = e0 + tid; i < e1; i += BSIZE)
        atomicAdd(&cnt[binned[i] & (BSIZE - 1)], 1);
    __syncthreads();

    int c = cnt[tid];
    lstart[tid] = c;
    __syncthreads();
    for (int ofs = 1; ofs < BSIZE; ofs <<= 1) {
        int t = (tid >= ofs) ? lstart[tid - ofs] : 0;
        __syncthreads();
        lstart[tid] += t;
        __syncthreads();
    }
    int excl = lstart[tid] - c;
    __syncthreads();
    lstart[tid] = excl;
    cnt[tid] = 0;
    __syncthreads();

    int n = n0 + tid;
    if (n < N) row_ptr[n] = e0 + excl;
    if (b == 0 && tid == 0) row_ptr[N] = E;

    for (int i = e0 + tid; i < e1; i += BSIZE) {
        unsigned int v = binned[i];          // L2-warm re-read
        int dl = v & (BSIZE - 1);
        int r = atomicAdd(&cnt[dl], 1);
        col[e0 + lstart[dl] + r] = (int)(v >> BSHIFT);
    }
}

// ---- Layer 1 node prep: rec[n] = {h[8], a_s[2], a_d[2], pad} ---------------

__global__ void prep1_kernel(const float* __restrict__ x,
                             const float* __restrict__ W1,   // [1,8]
                             const float* __restrict__ asw,  // [2,4]
                             const float* __restrict__ adw,  // [2,4]
                             int N,
                             float* __restrict__ rec) {      // [N,16]
    int n = blockIdx.x * blockDim.x + threadIdx.x;
    if (n >= N) return;
    float xv = x[n];
    float hv[8];
    #pragma unroll
    for (int j = 0; j < 8; ++j) hv[j] = xv * W1[j];
    float lg[4];  // a_s0, a_s1, a_d0, a_d1
    #pragma unroll
    for (int hd = 0; hd < 2; ++hd) {
        float s = 0.f, d = 0.f;
        #pragma unroll
        for (int f = 0; f < 4; ++f) {
            s += hv[hd * 4 + f] * asw[hd * 4 + f];
            d += hv[hd * 4 + f] * adw[hd * 4 + f];
        }
        lg[hd] = s;
        lg[2 + hd] = d;
    }
    float4* rp = (float4*)(rec + (size_t)n * 16);
    rp[0] = make_float4(hv[0], hv[1], hv[2], hv[3]);
    rp[1] = make_float4(hv[4], hv[5], hv[6], hv[7]);
    rp[2] = make_float4(lg[0], lg[1], lg[2], lg[3]);
}

// ---- Layer 2 node prep: h = in @ W2 (8x8), same packed layout --------------

__global__ void prep2_kernel(const float* __restrict__ in,   // [N,8]
                             const float* __restrict__ W2,   // [8,8]
                             const float* __restrict__ asw,
                             const float* __restrict__ adw,
                             int N,
                             float* __restrict__ rec) {      // [N,16]
    int n = blockIdx.x * blockDim.x + threadIdx.x;
    if (n >= N) return;
    const float4* ip = (const float4*)(in + (size_t)n * 8);
    float4 i0 = ip[0], i1 = ip[1];
    float iv[8] = {i0.x, i0.y, i0.z, i0.w, i1.x, i1.y, i1.z, i1.w};
    float hv[8];
    #pragma unroll
    for (int j = 0; j < 8; ++j) {
        float acc = 0.f;
        #pragma unroll
        for (int k = 0; k < 8; ++k) acc += iv[k] * W2[k * 8 + j];
        hv[j] = acc;
    }
    float lg[4];
    #pragma unroll
    for (int hd = 0; hd < 2; ++hd) {
        float s = 0.f, d = 0.f;
        #pragma unroll
        for (int f = 0; f < 4; ++f) {
            s += hv[hd * 4 + f] * asw[hd * 4 + f];
            d += hv[hd * 4 + f] * adw[hd * 4 + f];
        }
        lg[hd] = s;
        lg[2 + hd] = d;
    }
    float4* rp = (float4*)(rec + (size_t)n * 16);
    rp[0] = make_float4(hv[0], hv[1], hv[2], hv[3]);
    rp[1] = make_float4(hv[4], hv[5], hv[6], hv[7]);
    rp[2] = make_float4(lg[0], lg[1], lg[2], lg[3]);
}

// ---- GAT aggregation: 4 lanes per dst, single-pass softmax -----------------

__global__ void gat_pass_kernel(const float* __restrict__ rec,   // [N,16]
                                const int* __restrict__ row_ptr,
                                const int* __restrict__ col,
                                const float* __restrict__ bias,  // [8]
                                int N,
                                float* __restrict__ out) {       // [N,8]
    int t = blockIdx.x * blockDim.x + threadIdx.x;
    int n = t >> 2;
    int lane = t & 3;
    if (n >= N) return;
    const float4* recv = (const float4*)rec;
    float4 r2self = recv[(size_t)n * 4 + 2];   // a_s0,a_s1,a_d0,a_d1
    float ad0 = r2self.z, ad1 = r2self.w;
    float sum0 = 0.f, sum1 = 0.f;
    float acc[8] = {0.f, 0.f, 0.f, 0.f, 0.f, 0.f, 0.f, 0.f};
    if (lane == 0) {   // self-loop term
        float p0 = expf(leaky(r2self.x + ad0));
        float p1 = expf(leaky(r2self.y + ad1));
        sum0 = p0; sum1 = p1;
        float4 h0 = recv[(size_t)n * 4 + 0];
        float4 h1 = recv[(size_t)n * 4 + 1];
        acc[0] = h0.x * p0; acc[1] = h0.y * p0; acc[2] = h0.z * p0; acc[3] = h0.w * p0;
        acc[4] = h1.x * p1; acc[5] = h1.y * p1; acc[6] = h1.z * p1; acc[7] = h1.w * p1;
    }
    int beg = row_ptr[n], end = row_ptr[n + 1];
    for (int i = beg + lane; i < end; i += 4) {
        int s = __builtin_nontemporal_load(&col[i]);
        size_t sb = (size_t)s * 4;
        float4 s2 = recv[sb + 2];
        float q0 = expf(leaky(s2.x + ad0));
        float q1 = expf(leaky(s2.y + ad1));
        float4 s0 = recv[sb + 0];
        float4 s1 = recv[sb + 1];
        sum0 += q0; sum1 += q1;
        acc[0] += s0.x * q0; acc[1] += s0.y * q0; acc[2] += s0.z * q0; acc[3] += s0.w * q0;
        acc[4] += s1.x * q1; acc[5] += s1.y * q1; acc[6] += s1.z * q1; acc[7] += s1.w * q1;
    }
    // reduce across the 4 lanes of this dst
    #pragma unroll
    for (int ofs = 1; ofs < 4; ofs <<= 1) {
        sum0 += __shfl_xor(sum0, ofs, 4);
        sum1 += __shfl_xor(sum1, ofs, 4);
        #pragma unroll
        for (int k = 0; k < 8; ++k) acc[k] += __shfl_xor(acc[k], ofs, 4);
    }
    if (lane == 0) {
        float inv0 = 1.0f / (sum0 + GAT_EPS);
        float inv1 = 1.0f / (sum1 + GAT_EPS);
        float4* op = (float4*)(out + (size_t)n * 8);
        op[0] = make_float4(acc[0] * inv0 + bias[0], acc[1] * inv0 + bias[1],
                            acc[2] * inv0 + bias[2], acc[3] * inv0 + bias[3]);
        op[1] = make_float4(acc[4] * inv1 + bias[4], acc[5] * inv1 + bias[5],
                            acc[6] * inv1 + bias[6], acc[7] * inv1 + bias[7]);
    }
}

// ---- Readout: y = [h2[src], h2[dst]] @ Wl + bl -----------------------------

__global__ void final_kernel(const float* __restrict__ h2,   // [N,8]
                             const int* __restrict__ srcq,
                             const int* __restrict__ dstq,
                             const float* __restrict__ Wl,    // [16,2]
                             const float* __restrict__ bl,    // [2]
                             int Q,
                             float* __restrict__ y) {         // [Q,2]
    int q = blockIdx.x * blockDim.x + threadIdx.x;
    if (q >= Q) return;
    int s = srcq[q];
    int d = dstq[q];
    const float4* sp = (const float4*)(h2 + (size_t)s * 8);
    const float4* dp = (const float4*)(h2 + (size_t)d * 8);
    float4 s0 = sp[0], s1 = sp[1];
    float4 d0 = dp[0], d1 = dp[1];
    float hs[8] = {s0.x, s0.y, s0.z, s0.w, s1.x, s1.y, s1.z, s1.w};
    float hd[8] = {d0.x, d0.y, d0.z, d0.w, d1.x, d1.y, d1.z, d1.w};
    float y0 = bl[0], y1 = bl[1];
    #pragma unroll
    for (int k = 0; k < 8; ++k) {
        y0 += hs[k] * Wl[k * 2 + 0];
        y1 += hs[k] * Wl[k * 2 + 1];
    }
    #pragma unroll
    for (int k = 0; k < 8; ++k) {
        y0 += hd[k] * Wl[(8 + k) * 2 + 0];
        y1 += hd[k] * Wl[(8 + k) * 2 + 1];
    }
    *(float2*)(y + (size_t)q * 2) = make_float2(y0, y1);
}

// ---- launch ----------------------------------------------------------------

static inline size_t align_up(size_t v, size_t a) { return (v + a - 1) & ~(a - 1); }

extern "C" void kernel_launch(void* const* d_in, const int* in_sizes, int n_in,
                              void* d_out, int out_size, void* d_ws, size_t ws_size,
                              hipStream_t stream) {
    const float* x    = (const float*)d_in[0];
    const int*   ei   = (const int*)d_in[1];
    const int*   srcq = (const int*)d_in[2];
    const int*   dstq = (const int*)d_in[3];
    const float* W1   = (const float*)d_in[4];
    const float* as1  = (const float*)d_in[5];
    const float* ad1  = (const float*)d_in[6];
    const float* b1   = (const float*)d_in[7];
    const float* W2   = (const float*)d_in[8];
    const float* as2  = (const float*)d_in[9];
    const float* ad2  = (const float*)d_in[10];
    const float* b2   = (const float*)d_in[11];
    const float* Wl   = (const float*)d_in[12];
    const float* bl   = (const float*)d_in[13];

    const int N = in_sizes[0];         // x is [N,1]
    const int E = in_sizes[1] / 2;     // edge_index [2,E]
    const int Q = in_sizes[2];
    const int NB = (N + BSIZE - 1) >> BSHIFT;   // <= 512 for N <= 262144

    const int* esrc = ei;
    const int* edst = ei + E;

    // ---- workspace carve (binned region aliased with rec/out1/out2)
    char* w = (char*)d_ws;
    int* col     = (int*)w;  w += align_up((size_t)E * 4, 256);
    int* row_ptr = (int*)w;  w += align_up((size_t)(N + 1) * 4, 256);
    int* bcnt    = (int*)w;  w += align_up((size_t)NBPAD * 4, 256);
    int* bbase   = (int*)w;  w += align_up((size_t)(NBPAD + 1) * 4, 256);
    int* bcursor = (int*)w;  w += align_up((size_t)NBPAD * 4, 256);
    // region X: binned (E uints = 25.6MB) during build; rec+out1+out2 after
    char* rx = w;
    unsigned int* binned = (unsigned int*)rx;
    float* rec  = (float*)rx;                 rx += align_up((size_t)N * 16 * 4, 256);
    float* out1 = (float*)rx;                 rx += align_up((size_t)N * 8 * 4, 256);
    float* out2 = (float*)rx;                 // 12.8 + 6.4 + 6.4 = 25.6MB

    const int BT = 256;
    int nodeBlocks = (N + BT - 1) / BT;
    int gatBlocks  = ((N * 4) + BT - 1) / BT;
    int qBlocks    = (Q + BT - 1) / BT;
    int k3Blocks   = (E + K3_TILE - 1) / K3_TILE;

    // ---- CSR build (bucketed, write-coalesced)
    hipMemsetAsync(bcnt, 0, (size_t)NBPAD * 4, stream);
    bucket_count_kernel<<<1024, BT, 0, stream>>>(edst, E, NB, bcnt);
    bucket_scan_kernel<<<1, NBPAD, 0, stream>>>(bcnt, NB, bbase, bcursor);
    bin_scatter_kernel<<<k3Blocks, K3_T, 0, stream>>>(esrc, edst, E, NB, bcursor, binned);
    bucket_build_kernel<<<NB, BSIZE, 0, stream>>>(binned, bbase, N, E, row_ptr, col);

    // ---- layer 1 (rec overwrites dead binned region)
    prep1_kernel<<<nodeBlocks, BT, 0, stream>>>(x, W1, as1, ad1, N, rec);
    gat_pass_kernel<<<gatBlocks, BT, 0, stream>>>(rec, row_ptr, col, b1, N, out1);

    // ---- layer 2
    prep2_kernel<<<nodeBlocks, BT, 0, stream>>>(out1, W2, as2, ad2, N, rec);
    gat_pass_kernel<<<gatBlocks, BT, 0, stream>>>(rec, row_ptr, col, b2, N, out2);

    // ---- readout
    final_kernel<<<qBlocks, BT, 0, stream>>>(out2, srcq, dstq, Wl, bl, Q, (float*)d_out);
}

// Round 4
// 354.947 us; speedup vs baseline: 5.0119x; 1.1444x over previous
//
#include <hip/hip_runtime.h>
#include <hip/hip_fp16.h>

#define NEG_SLOPE 0.2f
#define GAT_EPS 1e-16f

#define BSHIFT 9
#define BSIZE 512            // nodes per bucket
#define NBPAD 512            // max buckets supported (N <= 262144)

#define K3_T 512
#define K3_VPT 8
#define K3_TILE (K3_T * K3_VPT)

typedef _Float16 half8 __attribute__((ext_vector_type(8)));

static __device__ __forceinline__ float leaky(float v) {
    return v > 0.0f ? v : NEG_SLOPE * v;
}

// ---- K1: per-bucket edge histogram (LDS-aggregated) ------------------------

__global__ void bucket_count_kernel(const int* __restrict__ dst, int E, int NB,
                                    int* __restrict__ bcnt) {
    __shared__ int cnt[NBPAD];
    for (int i = threadIdx.x; i < NBPAD; i += blockDim.x) cnt[i] = 0;
    __syncthreads();
    int stride = gridDim.x * blockDim.x;
    for (int i = blockIdx.x * blockDim.x + threadIdx.x; i < E; i += stride)
        atomicAdd(&cnt[dst[i] >> BSHIFT], 1);
    __syncthreads();
    for (int i = threadIdx.x; i < NB; i += blockDim.x)
        if (cnt[i]) atomicAdd(&bcnt[i], cnt[i]);
}

// ---- K2: scan of bucket counts (single block) ------------------------------

__global__ __launch_bounds__(NBPAD) void bucket_scan_kernel(
        const int* __restrict__ bcnt, int NB,
        int* __restrict__ bbase, int* __restrict__ bcursor) {
    __shared__ int lds[NBPAD];
    int tid = threadIdx.x;
    int v = (tid < NB) ? bcnt[tid] : 0;
    lds[tid] = v;
    __syncthreads();
    for (int ofs = 1; ofs < NBPAD; ofs <<= 1) {
        int t = (tid >= ofs) ? lds[tid - ofs] : 0;
        __syncthreads();
        lds[tid] += t;
        __syncthreads();
    }
    int incl = lds[tid];
    int excl = incl - v;
    if (tid < NB) { bbase[tid] = excl; bcursor[tid] = excl; }
    if (tid == NB - 1) bbase[NB] = incl;   // == E
}

// ---- K3: bucketed scatter with LDS tile reorder ----------------------------
// packed value: (src << 9) | (dst & 511); requires N <= 2^18.

__global__ __launch_bounds__(K3_T) void bin_scatter_kernel(
        const int* __restrict__ src, const int* __restrict__ dst, int E, int NB,
        int* __restrict__ bcursor, unsigned int* __restrict__ binned) {
    __shared__ int cnt[NBPAD];
    __shared__ int lstart[NBPAD];
    __shared__ int gbase[NBPAD];
    __shared__ unsigned int buf[K3_TILE];
    __shared__ unsigned short tgtb[K3_TILE];
    const int tid = threadIdx.x;
    const int t0 = blockIdx.x * K3_TILE;

    cnt[tid] = 0;
    __syncthreads();

    int b[K3_VPT];
    unsigned int v[K3_VPT];
    #pragma unroll
    for (int k = 0; k < K3_VPT; ++k) {
        int i = t0 + k * K3_T + tid;   // coalesced
        b[k] = -1;
        if (i < E) {
            int d = dst[i];
            int s = src[i];
            b[k] = d >> BSHIFT;
            v[k] = ((unsigned int)s << BSHIFT) | (unsigned int)(d & (BSIZE - 1));
            atomicAdd(&cnt[b[k]], 1);
        }
    }
    __syncthreads();

    int c = cnt[tid];
    lstart[tid] = c;
    __syncthreads();
    for (int ofs = 1; ofs < NBPAD; ofs <<= 1) {
        int t = (tid >= ofs) ? lstart[tid - ofs] : 0;
        __syncthreads();
        lstart[tid] += t;
        __syncthreads();
    }
    int excl = lstart[tid] - c;
    // reserve global space for this tile's bucket segments
    if (tid < NB) gbase[tid] = c ? atomicAdd(&bcursor[tid], c) : 0;
    __syncthreads();
    lstart[tid] = excl;
    cnt[tid] = 0;
    __syncthreads();

    // rank + reorder into LDS (bucket-sorted)
    #pragma unroll
    for (int k = 0; k < K3_VPT; ++k) {
        if (b[k] >= 0) {
            int r = atomicAdd(&cnt[b[k]], 1);
            int slot = lstart[b[k]] + r;
            buf[slot] = v[k];
            tgtb[slot] = (unsigned short)b[k];
        }
    }
    __syncthreads();

    // write out: consecutive slots of the same bucket -> consecutive addresses
    int nvalid = min(K3_TILE, E - t0);
    for (int j = tid; j < nvalid; j += K3_T) {
        int bb = tgtb[j];
        binned[gbase[bb] + (j - lstart[bb])] = buf[j];
    }
}

// ---- K4: per-bucket local scatter -> col + row_ptr -------------------------

__global__ __launch_bounds__(BSIZE) void bucket_build_kernel(
        const unsigned int* __restrict__ binned, const int* __restrict__ bbase,
        int N, int E, int* __restrict__ row_ptr, int* __restrict__ col) {
    __shared__ int cnt[BSIZE];
    __shared__ int lstart[BSIZE];
    const int b = blockIdx.x;
    const int tid = threadIdx.x;
    const int e0 = bbase[b], e1 = bbase[b + 1];
    const int n0 = b << BSHIFT;

    cnt[tid] = 0;
    __syncthreads();
    for (int i = e0 + tid; i < e1; i += BSIZE)
        atomicAdd(&cnt[binned[i] & (BSIZE - 1)], 1);
    __syncthreads();

    int c = cnt[tid];
    lstart[tid] = c;
    __syncthreads();
    for (int ofs = 1; ofs < BSIZE; ofs <<= 1) {
        int t = (tid >= ofs) ? lstart[tid - ofs] : 0;
        __syncthreads();
        lstart[tid] += t;
        __syncthreads();
    }
    int excl = lstart[tid] - c;
    __syncthreads();
    lstart[tid] = excl;
    cnt[tid] = 0;
    __syncthreads();

    int n = n0 + tid;
    if (n < N) row_ptr[n] = e0 + excl;
    if (b == 0 && tid == 0) row_ptr[N] = E;

    for (int i = e0 + tid; i < e1; i += BSIZE) {
        unsigned int v = binned[i];          // L2-warm re-read
        int dl = v & (BSIZE - 1);
        int r = atomicAdd(&cnt[dl], 1);
        col[e0 + lstart[dl] + r] = (int)(v >> BSHIFT);
    }
}

// ---- Layer 1 node prep: tables asrc/adst (fp32), h16 (fp16) ----------------

__global__ void prep1_kernel(const float* __restrict__ x,
                             const float* __restrict__ W1,   // [1,8]
                             const float* __restrict__ asw,  // [2,4]
                             const float* __restrict__ adw,  // [2,4]
                             int N,
                             float2* __restrict__ asrc,      // [N]
                             float2* __restrict__ adst,      // [N]
                             half8* __restrict__ h16) {      // [N]
    int n = blockIdx.x * blockDim.x + threadIdx.x;
    if (n >= N) return;
    float xv = x[n];
    float hv[8];
    #pragma unroll
    for (int j = 0; j < 8; ++j) hv[j] = xv * W1[j];
    float s0 = 0.f, s1 = 0.f, d0 = 0.f, d1 = 0.f;
    #pragma unroll
    for (int f = 0; f < 4; ++f) {
        s0 += hv[f] * asw[f];
        s1 += hv[4 + f] * asw[4 + f];
        d0 += hv[f] * adw[f];
        d1 += hv[4 + f] * adw[4 + f];
    }
    asrc[n] = make_float2(s0, s1);
    adst[n] = make_float2(d0, d1);
    half8 ho;
    #pragma unroll
    for (int j = 0; j < 8; ++j) ho[j] = (_Float16)hv[j];
    h16[n] = ho;
}

// ---- Layer 2 node prep: h = in @ W2 (8x8) ----------------------------------

__global__ void prep2_kernel(const float* __restrict__ in,   // [N,8]
                             const float* __restrict__ W2,   // [8,8]
                             const float* __restrict__ asw,
                             const float* __restrict__ adw,
                             int N,
                             float2* __restrict__ asrc,
                             float2* __restrict__ adst,
                             half8* __restrict__ h16) {
    int n = blockIdx.x * blockDim.x + threadIdx.x;
    if (n >= N) return;
    const float4* ip = (const float4*)(in + (size_t)n * 8);
    float4 i0 = ip[0], i1 = ip[1];
    float iv[8] = {i0.x, i0.y, i0.z, i0.w, i1.x, i1.y, i1.z, i1.w};
    float hv[8];
    #pragma unroll
    for (int j = 0; j < 8; ++j) {
        float acc = 0.f;
        #pragma unroll
        for (int k = 0; k < 8; ++k) acc += iv[k] * W2[k * 8 + j];
        hv[j] = acc;
    }
    float s0 = 0.f, s1 = 0.f, d0 = 0.f, d1 = 0.f;
    #pragma unroll
    for (int f = 0; f < 4; ++f) {
        s0 += hv[f] * asw[f];
        s1 += hv[4 + f] * asw[4 + f];
        d0 += hv[f] * adw[f];
        d1 += hv[4 + f] * adw[4 + f];
    }
    asrc[n] = make_float2(s0, s1);
    adst[n] = make_float2(d0, d1);
    half8 ho;
    #pragma unroll
    for (int j = 0; j < 8; ++j) ho[j] = (_Float16)hv[j];
    h16[n] = ho;
}

// ---- GAT aggregation: 8 lanes per dst, single-pass softmax -----------------

__global__ void gat_pass_kernel(const float2* __restrict__ asrc,   // [N]
                                const float2* __restrict__ adst,   // [N]
                                const half8* __restrict__ h16,     // [N]
                                const int* __restrict__ row_ptr,
                                const int* __restrict__ col,
                                const float* __restrict__ bias,    // [8]
                                int N,
                                float* __restrict__ out) {         // [N,8]
    int t = blockIdx.x * blockDim.x + threadIdx.x;
    int n = t >> 3;
    int lane = t & 7;
    if (n >= N) return;
    float2 ad = adst[n];
    float sum0 = 0.f, sum1 = 0.f;
    float acc[8] = {0.f, 0.f, 0.f, 0.f, 0.f, 0.f, 0.f, 0.f};
    if (lane == 0) {   // self-loop term
        float2 as0 = asrc[n];
        float p0 = expf(leaky(as0.x + ad.x));
        float p1 = expf(leaky(as0.y + ad.y));
        sum0 = p0; sum1 = p1;
        half8 hh = h16[n];
        acc[0] = (float)hh[0] * p0; acc[1] = (float)hh[1] * p0;
        acc[2] = (float)hh[2] * p0; acc[3] = (float)hh[3] * p0;
        acc[4] = (float)hh[4] * p1; acc[5] = (float)hh[5] * p1;
        acc[6] = (float)hh[6] * p1; acc[7] = (float)hh[7] * p1;
    }
    int beg = row_ptr[n], end = row_ptr[n + 1];
    for (int i = beg + lane; i < end; i += 8) {
        int s = __builtin_nontemporal_load(&col[i]);
        float2 a = asrc[s];
        float q0 = expf(leaky(a.x + ad.x));
        float q1 = expf(leaky(a.y + ad.y));
        half8 hh = h16[s];
        sum0 += q0; sum1 += q1;
        acc[0] += (float)hh[0] * q0; acc[1] += (float)hh[1] * q0;
        acc[2] += (float)hh[2] * q0; acc[3] += (float)hh[3] * q0;
        acc[4] += (float)hh[4] * q1; acc[5] += (float)hh[5] * q1;
        acc[6] += (float)hh[6] * q1; acc[7] += (float)hh[7] * q1;
    }
    // reduce across the 8 lanes of this dst
    #pragma unroll
    for (int ofs = 1; ofs < 8; ofs <<= 1) {
        sum0 += __shfl_xor(sum0, ofs, 8);
        sum1 += __shfl_xor(sum1, ofs, 8);
        #pragma unroll
        for (int k = 0; k < 8; ++k) acc[k] += __shfl_xor(acc[k], ofs, 8);
    }
    if (lane == 0) {
        float inv0 = 1.0f / (sum0 + GAT_EPS);
        float inv1 = 1.0f / (sum1 + GAT_EPS);
        float4* op = (float4*)(out + (size_t)n * 8);
        op[0] = make_float4(acc[0] * inv0 + bias[0], acc[1] * inv0 + bias[1],
                            acc[2] * inv0 + bias[2], acc[3] * inv0 + bias[3]);
        op[1] = make_float4(acc[4] * inv1 + bias[4], acc[5] * inv1 + bias[5],
                            acc[6] * inv1 + bias[6], acc[7] * inv1 + bias[7]);
    }
}

// ---- Readout: y = [h2[src], h2[dst]] @ Wl + bl -----------------------------

__global__ void final_kernel(const float* __restrict__ h2,   // [N,8]
                             const int* __restrict__ srcq,
                             const int* __restrict__ dstq,
                             const float* __restrict__ Wl,    // [16,2]
                             const float* __restrict__ bl,    // [2]
                             int Q,
                             float* __restrict__ y) {         // [Q,2]
    int q = blockIdx.x * blockDim.x + threadIdx.x;
    if (q >= Q) return;
    int s = srcq[q];
    int d = dstq[q];
    const float4* sp = (const float4*)(h2 + (size_t)s * 8);
    const float4* dp = (const float4*)(h2 + (size_t)d * 8);
    float4 s0 = sp[0], s1 = sp[1];
    float4 d0 = dp[0], d1 = dp[1];
    float hs[8] = {s0.x, s0.y, s0.z, s0.w, s1.x, s1.y, s1.z, s1.w};
    float hd[8] = {d0.x, d0.y, d0.z, d0.w, d1.x, d1.y, d1.z, d1.w};
    float y0 = bl[0], y1 = bl[1];
    #pragma unroll
    for (int k = 0; k < 8; ++k) {
        y0 += hs[k] * Wl[k * 2 + 0];
        y1 += hs[k] * Wl[k * 2 + 1];
    }
    #pragma unroll
    for (int k = 0; k < 8; ++k) {
        y0 += hd[k] * Wl[(8 + k) * 2 + 0];
        y1 += hd[k] * Wl[(8 + k) * 2 + 1];
    }
    *(float2*)(y + (size_t)q * 2) = make_float2(y0, y1);
}

// ---- launch ----------------------------------------------------------------

static inline size_t align_up(size_t v, size_t a) { return (v + a - 1) & ~(a - 1); }

extern "C" void kernel_launch(void* const* d_in, const int* in_sizes, int n_in,
                              void* d_out, int out_size, void* d_ws, size_t ws_size,
                              hipStream_t stream) {
    const float* x    = (const float*)d_in[0];
    const int*   ei   = (const int*)d_in[1];
    const int*   srcq = (const int*)d_in[2];
    const int*   dstq = (const int*)d_in[3];
    const float* W1   = (const float*)d_in[4];
    const float* as1  = (const float*)d_in[5];
    const float* ad1  = (const float*)d_in[6];
    const float* b1   = (const float*)d_in[7];
    const float* W2   = (const float*)d_in[8];
    const float* as2  = (const float*)d_in[9];
    const float* ad2  = (const float*)d_in[10];
    const float* b2   = (const float*)d_in[11];
    const float* Wl   = (const float*)d_in[12];
    const float* bl   = (const float*)d_in[13];

    const int N = in_sizes[0];         // x is [N,1]
    const int E = in_sizes[1] / 2;     // edge_index [2,E]
    const int Q = in_sizes[2];
    const int NB = (N + BSIZE - 1) >> BSHIFT;   // <= 512 for N <= 262144

    const int* esrc = ei;
    const int* edst = ei + E;

    // ---- workspace carve (binned region aliased with gather tables + outs)
    char* w = (char*)d_ws;
    int* col     = (int*)w;  w += align_up((size_t)E * 4, 256);
    int* row_ptr = (int*)w;  w += align_up((size_t)(N + 1) * 4, 256);
    int* bcnt    = (int*)w;  w += align_up((size_t)NBPAD * 4, 256);
    int* bbase   = (int*)w;  w += align_up((size_t)(NBPAD + 1) * 4, 256);
    int* bcursor = (int*)w;  w += align_up((size_t)NBPAD * 4, 256);
    // region X: binned (E uints = 25.6MB) during build; tables + outs after
    char* rx = w;
    unsigned int* binned = (unsigned int*)rx;
    half8*  h16  = (half8*)rx;                rx += align_up((size_t)N * 16, 256);
    float2* asrc = (float2*)rx;               rx += align_up((size_t)N * 8, 256);
    float2* adst = (float2*)rx;               rx += align_up((size_t)N * 8, 256);
    float*  out1 = (float*)rx;                rx += align_up((size_t)N * 8 * 4, 256);
    float*  out2 = (float*)rx;                // 3.2+1.6+1.6+6.4+6.4 = 19.2MB <= 25.6MB

    const int BT = 256;
    int nodeBlocks = (N + BT - 1) / BT;
    int gatBlocks  = ((N * 8) + BT - 1) / BT;
    int qBlocks    = (Q + BT - 1) / BT;
    int k3Blocks   = (E + K3_TILE - 1) / K3_TILE;

    // ---- CSR build (bucketed, write-coalesced)
    hipMemsetAsync(bcnt, 0, (size_t)NBPAD * 4, stream);
    bucket_count_kernel<<<1024, BT, 0, stream>>>(edst, E, NB, bcnt);
    bucket_scan_kernel<<<1, NBPAD, 0, stream>>>(bcnt, NB, bbase, bcursor);
    bin_scatter_kernel<<<k3Blocks, K3_T, 0, stream>>>(esrc, edst, E, NB, bcursor, binned);
    bucket_build_kernel<<<NB, BSIZE, 0, stream>>>(binned, bbase, N, E, row_ptr, col);

    // ---- layer 1 (tables overwrite dead binned region)
    prep1_kernel<<<nodeBlocks, BT, 0, stream>>>(x, W1, as1, ad1, N, asrc, adst, h16);
    gat_pass_kernel<<<gatBlocks, BT, 0, stream>>>(asrc, adst, h16, row_ptr, col, b1, N, out1);

    // ---- layer 2
    prep2_kernel<<<nodeBlocks, BT, 0, stream>>>(out1, W2, as2, ad2, N, asrc, adst, h16);
    gat_pass_kernel<<<gatBlocks, BT, 0, stream>>>(asrc, adst, h16, row_ptr, col, b2, N, out2);

    // ---- readout
    final_kernel<<<qBlocks, BT, 0, stream>>>(out2, srcq, dstq, Wl, bl, Q, (float*)d_out);
}

// Round 5
// 264.658 us; speedup vs baseline: 6.7217x; 1.3412x over previous
//
#include <hip/hip_runtime.h>
#include <hip/hip_fp16.h>

#define NEG_SLOPE 0.2f
#define GAT_EPS 1e-16f

#define BSHIFT 9
#define BSIZE 512            // nodes per bucket
#define NBPAD 512            // max buckets supported (N <= 262144)

#define K3_T 512
#define K3_VPT 8
#define K3_TILE (K3_T * K3_VPT)

typedef _Float16 half8 __attribute__((ext_vector_type(8)));

static __device__ __forceinline__ float leaky(float v) {
    return v > 0.0f ? v : NEG_SLOPE * v;
}

// ---- K1: per-bucket edge histogram (LDS-aggregated) ------------------------

__global__ void bucket_count_kernel(const int* __restrict__ dst, int E, int NB,
                                    int* __restrict__ bcnt) {
    __shared__ int cnt[NBPAD];
    for (int i = threadIdx.x; i < NBPAD; i += blockDim.x) cnt[i] = 0;
    __syncthreads();
    int stride = gridDim.x * blockDim.x;
    for (int i = blockIdx.x * blockDim.x + threadIdx.x; i < E; i += stride)
        atomicAdd(&cnt[dst[i] >> BSHIFT], 1);
    __syncthreads();
    for (int i = threadIdx.x; i < NB; i += blockDim.x)
        if (cnt[i]) atomicAdd(&bcnt[i], cnt[i]);
}

// ---- K2: scan of bucket counts (single block) ------------------------------

__global__ __launch_bounds__(NBPAD) void bucket_scan_kernel(
        const int* __restrict__ bcnt, int NB,
        int* __restrict__ bbase, int* __restrict__ bcursor) {
    __shared__ int lds[NBPAD];
    int tid = threadIdx.x;
    int v = (tid < NB) ? bcnt[tid] : 0;
    lds[tid] = v;
    __syncthreads();
    for (int ofs = 1; ofs < NBPAD; ofs <<= 1) {
        int t = (tid >= ofs) ? lds[tid - ofs] : 0;
        __syncthreads();
        lds[tid] += t;
        __syncthreads();
    }
    int incl = lds[tid];
    int excl = incl - v;
    if (tid < NB) { bbase[tid] = excl; bcursor[tid] = excl; }
    if (tid == NB - 1) bbase[NB] = incl;   // == E
}

// ---- K3: bucketed scatter with LDS tile reorder ----------------------------
// packed value: (src << 9) | (dst & 511); requires N <= 2^18.

__global__ __launch_bounds__(K3_T) void bin_scatter_kernel(
        const int* __restrict__ src, const int* __restrict__ dst, int E, int NB,
        int* __restrict__ bcursor, unsigned int* __restrict__ binned) {
    __shared__ int cnt[NBPAD];
    __shared__ int lstart[NBPAD];
    __shared__ int gbase[NBPAD];
    __shared__ unsigned int buf[K3_TILE];
    __shared__ unsigned short tgtb[K3_TILE];
    const int tid = threadIdx.x;
    const int t0 = blockIdx.x * K3_TILE;

    cnt[tid] = 0;
    __syncthreads();

    int b[K3_VPT];
    unsigned int v[K3_VPT];
    #pragma unroll
    for (int k = 0; k < K3_VPT; ++k) {
        int i = t0 + k * K3_T + tid;   // coalesced
        b[k] = -1;
        if (i < E) {
            int d = dst[i];
            int s = src[i];
            b[k] = d >> BSHIFT;
            v[k] = ((unsigned int)s << BSHIFT) | (unsigned int)(d & (BSIZE - 1));
            atomicAdd(&cnt[b[k]], 1);
        }
    }
    __syncthreads();

    int c = cnt[tid];
    lstart[tid] = c;
    __syncthreads();
    for (int ofs = 1; ofs < NBPAD; ofs <<= 1) {
        int t = (tid >= ofs) ? lstart[tid - ofs] : 0;
        __syncthreads();
        lstart[tid] += t;
        __syncthreads();
    }
    int excl = lstart[tid] - c;
    // reserve global space for this tile's bucket segments
    if (tid < NB) gbase[tid] = c ? atomicAdd(&bcursor[tid], c) : 0;
    __syncthreads();
    lstart[tid] = excl;
    cnt[tid] = 0;
    __syncthreads();

    // rank + reorder into LDS (bucket-sorted)
    #pragma unroll
    for (int k = 0; k < K3_VPT; ++k) {
        if (b[k] >= 0) {
            int r = atomicAdd(&cnt[b[k]], 1);
            int slot = lstart[b[k]] + r;
            buf[slot] = v[k];
            tgtb[slot] = (unsigned short)b[k];
        }
    }
    __syncthreads();

    // write out: consecutive slots of the same bucket -> consecutive addresses
    int nvalid = min(K3_TILE, E - t0);
    for (int j = tid; j < nvalid; j += K3_T) {
        int bb = tgtb[j];
        binned[gbase[bb] + (j - lstart[bb])] = buf[j];
    }
}

// ---- K4: per-bucket local scatter -> col + row_ptr -------------------------

__global__ __launch_bounds__(BSIZE) void bucket_build_kernel(
        const unsigned int* __restrict__ binned, const int* __restrict__ bbase,
        int N, int E, int* __restrict__ row_ptr, int* __restrict__ col) {
    __shared__ int cnt[BSIZE];
    __shared__ int lstart[BSIZE];
    const int b = blockIdx.x;
    const int tid = threadIdx.x;
    const int e0 = bbase[b], e1 = bbase[b + 1];
    const int n0 = b << BSHIFT;

    cnt[tid] = 0;
    __syncthreads();
    for (int i = e0 + tid; i < e1; i += BSIZE)
        atomicAdd(&cnt[binned[i] & (BSIZE - 1)], 1);
    __syncthreads();

    int c = cnt[tid];
    lstart[tid] = c;
    __syncthreads();
    for (int ofs = 1; ofs < BSIZE; ofs <<= 1) {
        int t = (tid >= ofs) ? lstart[tid - ofs] : 0;
        __syncthreads();
        lstart[tid] += t;
        __syncthreads();
    }
    int excl = lstart[tid] - c;
    __syncthreads();
    lstart[tid] = excl;
    cnt[tid] = 0;
    __syncthreads();

    int n = n0 + tid;
    if (n < N) row_ptr[n] = e0 + excl;
    if (b == 0 && tid == 0) row_ptr[N] = E;

    for (int i = e0 + tid; i < e1; i += BSIZE) {
        unsigned int v = binned[i];          // L2-warm re-read
        int dl = v & (BSIZE - 1);
        int r = atomicAdd(&cnt[dl], 1);
        col[e0 + lstart[dl] + r] = (int)(v >> BSHIFT);
    }
}

// ---- Layer 1 node prep: h16 (fp16 [N]), adst (fp32 [N,2]) ------------------

__global__ void prep1_kernel(const float* __restrict__ x,
                             const float* __restrict__ W1,   // [1,8]
                             const float* __restrict__ adw,  // [2,4]
                             int N,
                             float2* __restrict__ adst,
                             half8* __restrict__ h16) {
    int n = blockIdx.x * blockDim.x + threadIdx.x;
    if (n >= N) return;
    float xv = x[n];
    float hv[8];
    #pragma unroll
    for (int j = 0; j < 8; ++j) hv[j] = xv * W1[j];
    float d0 = 0.f, d1 = 0.f;
    #pragma unroll
    for (int f = 0; f < 4; ++f) {
        d0 += hv[f] * adw[f];
        d1 += hv[4 + f] * adw[4 + f];
    }
    adst[n] = make_float2(d0, d1);
    half8 ho;
    #pragma unroll
    for (int j = 0; j < 8; ++j) ho[j] = (_Float16)hv[j];
    h16[n] = ho;
}

// ---- Layer 2 node prep: h = in @ W2 (8x8) ----------------------------------

__global__ void prep2_kernel(const float* __restrict__ in,   // [N,8] fp32
                             const float* __restrict__ W2,   // [8,8]
                             const float* __restrict__ adw,
                             int N,
                             float2* __restrict__ adst,
                             half8* __restrict__ h16) {
    int n = blockIdx.x * blockDim.x + threadIdx.x;
    if (n >= N) return;
    const float4* ip = (const float4*)(in + (size_t)n * 8);
    float4 i0 = ip[0], i1 = ip[1];
    float iv[8] = {i0.x, i0.y, i0.z, i0.w, i1.x, i1.y, i1.z, i1.w};
    float hv[8];
    #pragma unroll
    for (int j = 0; j < 8; ++j) {
        float acc = 0.f;
        #pragma unroll
        for (int k = 0; k < 8; ++k) acc += iv[k] * W2[k * 8 + j];
        hv[j] = acc;
    }
    float d0 = 0.f, d1 = 0.f;
    #pragma unroll
    for (int f = 0; f < 4; ++f) {
        d0 += hv[f] * adw[f];
        d1 += hv[4 + f] * adw[4 + f];
    }
    adst[n] = make_float2(d0, d1);
    half8 ho;
    #pragma unroll
    for (int j = 0; j < 8; ++j) ho[j] = (_Float16)hv[j];
    h16[n] = ho;
}

// ---- GAT aggregation: 8 lanes/dst, 1x16B gather/edge, src-logit on the fly -

__global__ void gat_pass_kernel(const float2* __restrict__ adst,   // [N]
                                const half8* __restrict__ h16,     // [N]
                                const int* __restrict__ row_ptr,
                                const int* __restrict__ col,
                                const float* __restrict__ asw,     // [2,4]
                                const float* __restrict__ bias,    // [8]
                                int N,
                                float* __restrict__ out32,         // [N,8] or null
                                half8* __restrict__ out16) {       // [N] or null
    int t = blockIdx.x * blockDim.x + threadIdx.x;
    int n = t >> 3;
    int lane = t & 7;
    if (n >= N) return;
    float w0 = asw[0], w1 = asw[1], w2 = asw[2], w3 = asw[3];
    float w4 = asw[4], w5 = asw[5], w6 = asw[6], w7 = asw[7];
    float2 ad = adst[n];
    float sum0 = 0.f, sum1 = 0.f;
    float acc[8] = {0.f, 0.f, 0.f, 0.f, 0.f, 0.f, 0.f, 0.f};
    if (lane == 0) {   // self-loop term
        half8 hh = h16[n];
        float hs[8];
        #pragma unroll
        for (int k = 0; k < 8; ++k) hs[k] = (float)hh[k];
        float a0 = hs[0] * w0 + hs[1] * w1 + hs[2] * w2 + hs[3] * w3;
        float a1 = hs[4] * w4 + hs[5] * w5 + hs[6] * w6 + hs[7] * w7;
        float p0 = expf(leaky(a0 + ad.x));
        float p1 = expf(leaky(a1 + ad.y));
        sum0 = p0; sum1 = p1;
        #pragma unroll
        for (int k = 0; k < 4; ++k) { acc[k] = hs[k] * p0; acc[4 + k] = hs[4 + k] * p1; }
    }
    int beg = row_ptr[n], end = row_ptr[n + 1];
    for (int i = beg + lane; i < end; i += 8) {
        int s = __builtin_nontemporal_load(&col[i]);
        half8 hh = h16[s];                      // single 16B gather
        float hs[8];
        #pragma unroll
        for (int k = 0; k < 8; ++k) hs[k] = (float)hh[k];
        float a0 = hs[0] * w0 + hs[1] * w1 + hs[2] * w2 + hs[3] * w3;
        float a1 = hs[4] * w4 + hs[5] * w5 + hs[6] * w6 + hs[7] * w7;
        float q0 = expf(leaky(a0 + ad.x));
        float q1 = expf(leaky(a1 + ad.y));
        sum0 += q0; sum1 += q1;
        #pragma unroll
        for (int k = 0; k < 4; ++k) { acc[k] += hs[k] * q0; acc[4 + k] += hs[4 + k] * q1; }
    }
    // reduce across the 8 lanes of this dst
    #pragma unroll
    for (int ofs = 1; ofs < 8; ofs <<= 1) {
        sum0 += __shfl_xor(sum0, ofs, 8);
        sum1 += __shfl_xor(sum1, ofs, 8);
        #pragma unroll
        for (int k = 0; k < 8; ++k) acc[k] += __shfl_xor(acc[k], ofs, 8);
    }
    if (lane == 0) {
        float inv0 = 1.0f / (sum0 + GAT_EPS);
        float inv1 = 1.0f / (sum1 + GAT_EPS);
        float r[8];
        #pragma unroll
        for (int k = 0; k < 4; ++k) {
            r[k] = acc[k] * inv0 + bias[k];
            r[4 + k] = acc[4 + k] * inv1 + bias[4 + k];
        }
        if (out32) {
            float4* op = (float4*)(out32 + (size_t)n * 8);
            op[0] = make_float4(r[0], r[1], r[2], r[3]);
            op[1] = make_float4(r[4], r[5], r[6], r[7]);
        }
        if (out16) {
            half8 ho;
            #pragma unroll
            for (int k = 0; k < 8; ++k) ho[k] = (_Float16)r[k];
            out16[n] = ho;
        }
    }
}

// ---- Readout: y = [h2[src], h2[dst]] @ Wl + bl  (h2 fp16, L2-resident) -----

__global__ void final_kernel(const half8* __restrict__ h2,    // [N]
                             const int* __restrict__ srcq,
                             const int* __restrict__ dstq,
                             const float* __restrict__ Wl,    // [16,2]
                             const float* __restrict__ bl,    // [2]
                             int Q,
                             float* __restrict__ y) {         // [Q,2]
    int q = blockIdx.x * blockDim.x + threadIdx.x;
    if (q >= Q) return;
    int s = srcq[q];
    int d = dstq[q];
    half8 hs8 = h2[s];
    half8 hd8 = h2[d];
    float y0 = bl[0], y1 = bl[1];
    #pragma unroll
    for (int k = 0; k < 8; ++k) {
        float hv = (float)hs8[k];
        y0 += hv * Wl[k * 2 + 0];
        y1 += hv * Wl[k * 2 + 1];
    }
    #pragma unroll
    for (int k = 0; k < 8; ++k) {
        float hv = (float)hd8[k];
        y0 += hv * Wl[(8 + k) * 2 + 0];
        y1 += hv * Wl[(8 + k) * 2 + 1];
    }
    *(float2*)(y + (size_t)q * 2) = make_float2(y0, y1);
}

// ---- launch ----------------------------------------------------------------

static inline size_t align_up(size_t v, size_t a) { return (v + a - 1) & ~(a - 1); }

extern "C" void kernel_launch(void* const* d_in, const int* in_sizes, int n_in,
                              void* d_out, int out_size, void* d_ws, size_t ws_size,
                              hipStream_t stream) {
    const float* x    = (const float*)d_in[0];
    const int*   ei   = (const int*)d_in[1];
    const int*   srcq = (const int*)d_in[2];
    const int*   dstq = (const int*)d_in[3];
    const float* W1   = (const float*)d_in[4];
    const float* as1  = (const float*)d_in[5];
    const float* ad1  = (const float*)d_in[6];
    const float* b1   = (const float*)d_in[7];
    const float* W2   = (const float*)d_in[8];
    const float* as2  = (const float*)d_in[9];
    const float* ad2  = (const float*)d_in[10];
    const float* b2   = (const float*)d_in[11];
    const float* Wl   = (const float*)d_in[12];
    const float* bl   = (const float*)d_in[13];

    const int N = in_sizes[0];         // x is [N,1]
    const int E = in_sizes[1] / 2;     // edge_index [2,E]
    const int Q = in_sizes[2];
    const int NB = (N + BSIZE - 1) >> BSHIFT;   // <= 512 for N <= 262144

    const int* esrc = ei;
    const int* edst = ei + E;

    // ---- workspace carve (binned region aliased with gather tables + outs)
    char* w = (char*)d_ws;
    int* col     = (int*)w;  w += align_up((size_t)E * 4, 256);
    int* row_ptr = (int*)w;  w += align_up((size_t)(N + 1) * 4, 256);
    int* bcnt    = (int*)w;  w += align_up((size_t)NBPAD * 4, 256);
    int* bbase   = (int*)w;  w += align_up((size_t)(NBPAD + 1) * 4, 256);
    int* bcursor = (int*)w;  w += align_up((size_t)NBPAD * 4, 256);
    // region X: binned (E uints = 25.6MB) during build; tables + outs after
    char* rx = w;
    unsigned int* binned = (unsigned int*)rx;
    half8*  h16  = (half8*)rx;                rx += align_up((size_t)N * 16, 256);
    float2* adst = (float2*)rx;               rx += align_up((size_t)N * 8, 256);
    float*  out1 = (float*)rx;                rx += align_up((size_t)N * 8 * 4, 256);
    half8*  out2h = (half8*)rx;               // 3.2+1.6+6.4+3.2 = 14.4MB <= 25.6MB

    const int BT = 256;
    int nodeBlocks = (N + BT - 1) / BT;
    int gatBlocks  = ((N * 8) + BT - 1) / BT;
    int qBlocks    = (Q + BT - 1) / BT;
    int k3Blocks   = (E + K3_TILE - 1) / K3_TILE;

    // ---- CSR build (bucketed, write-coalesced)
    hipMemsetAsync(bcnt, 0, (size_t)NBPAD * 4, stream);
    bucket_count_kernel<<<1024, BT, 0, stream>>>(edst, E, NB, bcnt);
    bucket_scan_kernel<<<1, NBPAD, 0, stream>>>(bcnt, NB, bbase, bcursor);
    bin_scatter_kernel<<<k3Blocks, K3_T, 0, stream>>>(esrc, edst, E, NB, bcursor, binned);
    bucket_build_kernel<<<NB, BSIZE, 0, stream>>>(binned, bbase, N, E, row_ptr, col);

    // ---- layer 1 (tables overwrite dead binned region)
    prep1_kernel<<<nodeBlocks, BT, 0, stream>>>(x, W1, ad1, N, adst, h16);
    gat_pass_kernel<<<gatBlocks, BT, 0, stream>>>(adst, h16, row_ptr, col, as1, b1, N,
                                                  out1, (half8*)nullptr);

    // ---- layer 2
    prep2_kernel<<<nodeBlocks, BT, 0, stream>>>(out1, W2, ad2, N, adst, h16);
    gat_pass_kernel<<<gatBlocks, BT, 0, stream>>>(adst, h16, row_ptr, col, as2, b2, N,
                                                  (float*)nullptr, out2h);

    // ---- readout (h2 fp16 table, L2-resident)
    final_kernel<<<qBlocks, BT, 0, stream>>>(out2h, srcq, dstq, Wl, bl, Q, (float*)d_out);
}